// Round 6
// baseline (267.190 us; speedup 1.0000x reference)
//
#include <hip/hip_runtime.h>

// ============================================================================
// GPT-2 attention block on gfx950, bf16 MFMA throughout.
//
// R6:
//  - XOR-swizzled LDS staging (GEMMs + attn K/V): stage k-chunk
//    (lane&3)^((lane>>3)&3), read chunk quad^((l15>>1)&3). Kills the 8-way
//    bank conflict on ds_read_b128 fragment reads (SQ_LDS_BANK_CONFLICT 6.3M
//    -> ~0) with zero hot-loop instruction cost.
//  - Re-applied R3's pos-permutation of the P*V key axis (independently this
//    time): V^T stored with pos=(key&15)*4+(key>>4) per 64-block; P written
//    as bf16x4 ds_write_b64 (8/lane/iter vs 32 scalar b16).
//  - GEMMs stay BK=32 (m97); attn keeps R5 double-buffered K/V, 1 barrier/it.
// ============================================================================

typedef __bf16 bf16_t;
typedef __bf16 bf16x8 __attribute__((ext_vector_type(8)));
typedef __bf16 bf16x4 __attribute__((ext_vector_type(4)));
typedef float  f32x4  __attribute__((ext_vector_type(4)));

#define DI __device__ __forceinline__

static constexpr int Bq = 4, Sq = 2048, NXq = 1024, NHq = 16, HDq = 64;

DI void gl2lds16(const void* g, void* l) {
#if defined(__has_builtin)
#if __has_builtin(__builtin_amdgcn_global_load_lds)
  __builtin_amdgcn_global_load_lds(
      (const __attribute__((address_space(1))) void*)g,
      (__attribute__((address_space(3))) void*)l, 16, 0, 0);
  return;
#endif
#endif
  *(bf16x8*)l = *(const bf16x8*)g;
}

DI float fast_exp2(float x) {
#if defined(__has_builtin)
#if __has_builtin(__builtin_amdgcn_exp2f)
  return __builtin_amdgcn_exp2f(x);
#else
  return exp2f(x);
#endif
#else
  return exp2f(x);
#endif
}

// ---------------------------------------------------------------------------
// k0: fp32 -> bf16 convert
// ---------------------------------------------------------------------------
__global__ __launch_bounds__(256) void cvt_bf16(const float* __restrict__ in,
                                                bf16_t* __restrict__ out, int n) {
  int i = (blockIdx.x * 256 + threadIdx.x) * 4;
  if (i >= n) return;
  float4 v = *(const float4*)(in + i);
  bf16x4 o;
  o[0] = (bf16_t)v.x; o[1] = (bf16_t)v.y; o[2] = (bf16_t)v.z; o[3] = (bf16_t)v.w;
  *(bf16x4*)(out + i) = o;
}

// ---------------------------------------------------------------------------
// k1: transpose + convert
// ---------------------------------------------------------------------------
__global__ __launch_bounds__(256) void transpose_cvt(const float* __restrict__ in,
                                                     bf16_t* __restrict__ out,
                                                     int R, int C) {
  __shared__ float t[32][33];
  int bx = blockIdx.x * 32, by = blockIdx.y * 32;
  int tx = threadIdx.x, ty = threadIdx.y;
#pragma unroll
  for (int i = 0; i < 32; i += 8)
    t[ty + i][tx] = in[(size_t)(by + ty + i) * C + bx + tx];
  __syncthreads();
#pragma unroll
  for (int i = 0; i < 32; i += 8)
    out[(size_t)(bx + ty + i) * R + by + tx] = (bf16_t)t[tx][ty + i];
}

// ---------------------------------------------------------------------------
// GEMM main loop (m97 structure, BK=32) with XOR-swizzled staging.
// Chunk layout per 16-row group g: addr = g*512 + row_local*32 + schunk*8,
// where schunk = (lane&3)^((lane>>3)&3) at staging. Fragment read for
// (row_local=l15, k-chunk=quad) is at l15*32 + (quad^((l15>>1)&3))*8 ->
// banks 2-way only (free).
// ---------------------------------------------------------------------------
DI void gemm_main(const bf16_t* __restrict__ A, const bf16_t* __restrict__ Bt,
                  int K, f32x4 acc[4][4], bf16_t* As, bf16_t* Bs,
                  int lane, int w) {
  const int wy = w >> 1, wx = w & 1;
  const int l15 = lane & 15, quad = lane >> 4;
  const int sr = lane >> 2;
  const int sk = 8 * ((lane & 3) ^ ((lane >> 3) & 3));  // swizzled k-chunk
  const int qx = quad ^ ((l15 >> 1) & 3);               // read-side unswizzle
  for (int kt = 0; kt < K; kt += 32) {
    __syncthreads();
#pragma unroll
    for (int i = 0; i < 2; ++i) {
      int g = w * 2 + i;
      int row = g * 16 + sr;
      int ko = kt + sk;
      gl2lds16(A + (size_t)row * K + ko, As + g * 512 + lane * 8);
      gl2lds16(Bt + (size_t)row * K + ko, Bs + g * 512 + lane * 8);
    }
    __syncthreads();
    bf16x8 af[4], bfr[4];
#pragma unroll
    for (int mi = 0; mi < 4; ++mi)
      af[mi] = *(const bf16x8*)(As + (wy * 4 + mi) * 512 + l15 * 32 + qx * 8);
#pragma unroll
    for (int ni = 0; ni < 4; ++ni)
      bfr[ni] = *(const bf16x8*)(Bs + (wx * 4 + ni) * 512 + l15 * 32 + qx * 8);
#pragma unroll
    for (int mi = 0; mi < 4; ++mi)
#pragma unroll
      for (int ni = 0; ni < 4; ++ni)
        acc[mi][ni] = __builtin_amdgcn_mfma_f32_16x16x32_bf16(
            af[mi], bfr[ni], acc[mi][ni], 0, 0, 0);
  }
}

// ---------------------------------------------------------------------------
// k2: QKV GEMM. Q pre-scaled by 0.125*log2e -> [b,h,s,d]; K -> [b,h,s,d];
// V -> v^T[b,h,d,pos] with 64-block-local pos=(key&15)*4+(key>>4).
// ---------------------------------------------------------------------------
__global__ __launch_bounds__(256) void gemm_qkv(
    const bf16_t* __restrict__ X, const bf16_t* __restrict__ Wt,
    const float* __restrict__ bias, bf16_t* __restrict__ qw,
    bf16_t* __restrict__ kw, bf16_t* __restrict__ vtw) {
  __shared__ __align__(16) bf16_t As[128 * 32];
  __shared__ __align__(16) bf16_t Bs[128 * 32];
  const int tid = threadIdx.x, lane = tid & 63, w = tid >> 6;
  const int m0 = blockIdx.y * 128, n0 = blockIdx.x * 128;
  f32x4 acc[4][4];
#pragma unroll
  for (int mi = 0; mi < 4; ++mi)
#pragma unroll
    for (int ni = 0; ni < 4; ++ni) acc[mi][ni] = (f32x4){0.f, 0.f, 0.f, 0.f};
  gemm_main(X + (size_t)m0 * NXq, Wt + (size_t)n0 * NXq, NXq, acc, As, Bs, lane, w);

  const int wy = w >> 1, wx = w & 1, l15 = lane & 15, quad = lane >> 4;
  const float qscale = 0.125f * 1.44269504088896340736f;
#pragma unroll
  for (int mi = 0; mi < 4; ++mi) {
    int rowb = m0 + wy * 64 + mi * 16 + quad * 4;
    int bb = rowb >> 11, sl = rowb & 2047;
#pragma unroll
    for (int ni = 0; ni < 4; ++ni) {
      int col = n0 + wx * 64 + ni * 16 + l15;
      float bv = bias[col];
      f32x4 v = acc[mi][ni];
      int sec = col >> 10;
      int c = col & 1023;
      int h = c >> 6, d = c & 63;
      if (sec == 0) {
#pragma unroll
        for (int r = 0; r < 4; ++r)
          qw[(((size_t)bb * NHq + h) * Sq + sl + r) * HDq + d] =
              (bf16_t)((v[r] + bv) * qscale);
      } else if (sec == 1) {
#pragma unroll
        for (int r = 0; r < 4; ++r)
          kw[(((size_t)bb * NHq + h) * Sq + sl + r) * HDq + d] = (bf16_t)(v[r] + bv);
      } else {
        // pos-permuted V^T: key = sl64 + r (sl64 4-aligned, so key&15 =
        // (sl64&15)+r, key>>4 unchanged) -> pos = pos0 + 4r.
        int sl64 = sl & 63;
        int pos0 = (sl & ~63) + ((sl64 & 15) << 2) + (sl64 >> 4);
        bf16_t* vb = vtw + (((size_t)bb * NHq + h) * HDq + d) * Sq + pos0;
#pragma unroll
        for (int r = 0; r < 4; ++r) vb[4 * r] = (bf16_t)(v[r] + bv);
      }
    }
  }
}

// ---------------------------------------------------------------------------
// k3: flash attention, causal. BQ=128, BK=64, double-buffered K/V staging
// (one __syncthreads/iter), XOR-swizzled chunks, pos-permuted P*V key axis.
// ---------------------------------------------------------------------------
__global__ __launch_bounds__(256, 3) void attn_fwd(
    const bf16_t* __restrict__ qw, const bf16_t* __restrict__ kw,
    const bf16_t* __restrict__ vtw, bf16_t* __restrict__ aw) {
  __shared__ __align__(16) bf16_t Ks[2][4096], Vs[2][4096];
  __shared__ __align__(16) bf16_t Ps[4][32 * 72];
  const int tid = threadIdx.x, lane = tid & 63, w = tid >> 6;
  const int l15 = lane & 15, quad = lane >> 4;

  const int id = blockIdx.x;
  const int bh = ((id & 7) << 3) | ((id >> 3) & 7);
  const int k4 = (id >> 6) & 3, quarter = id >> 8;
  int qtile;
  if (quarter == 0)      qtile = 15 - k4;
  else if (quarter == 1) qtile = 8 + k4;
  else if (quarter == 2) qtile = 7 - k4;
  else                   qtile = k4;
  const int b = bh >> 4, h = bh & 15;

  const bf16_t* Qg = qw + ((size_t)bh * Sq + qtile * 128) * HDq;
  const bf16_t* Kg = kw + (size_t)bh * Sq * HDq;
  const bf16_t* Vg = vtw + (size_t)bh * HDq * Sq;

  const int su = w * 2, sr = lane >> 2;
  const int sk = 8 * ((lane & 3) ^ ((lane >> 3) & 3));  // swizzled chunk
  const int qx = quad ^ ((l15 >> 1) & 3);               // read-side unswizzle

  // prologue: stage tile 0 into buffer 0
#pragma unroll
  for (int i = 0; i < 2; ++i) {
    int u = su + i, p = u >> 2, g = u & 3;
    gl2lds16(Kg + (size_t)(g * 16 + sr) * HDq + p * 32 + sk, Ks[0] + u * 512 + lane * 8);
    gl2lds16(Vg + (size_t)(g * 16 + sr) * Sq + p * 32 + sk, Vs[0] + u * 512 + lane * 8);
  }

  bf16x8 qf[2][2];
#pragma unroll
  for (int mi = 0; mi < 2; ++mi)
#pragma unroll
    for (int ks = 0; ks < 2; ++ks)
      qf[mi][ks] = *(const bf16x8*)(
          Qg + (size_t)((w * 2 + mi) * 16 + l15) * HDq + ks * 32 + quad * 8);

  f32x4 o[2][4];
  float lsum[2][4];
#pragma unroll
  for (int mi = 0; mi < 2; ++mi) {
#pragma unroll
    for (int dt = 0; dt < 4; ++dt) o[mi][dt] = (f32x4){0.f, 0.f, 0.f, 0.f};
#pragma unroll
    for (int r = 0; r < 4; ++r) lsum[mi][r] = 0.f;
  }

  bf16_t* Pw = &Ps[w][0];
  const int jmax = 2 * qtile + 2;
  for (int jt = 0; jt < jmax; ++jt) {
    const int cur = jt & 1;
    __syncthreads();  // drains stage(jt); fences prev iter's LDS reads

    if (jt + 1 < jmax) {  // async prefetch of tile jt+1 into alt buffer
      const int nxt = cur ^ 1;
#pragma unroll
      for (int i = 0; i < 2; ++i) {
        int u = su + i, p = u >> 2, g = u & 3;
        gl2lds16(Kg + (size_t)((jt + 1) * 64 + g * 16 + sr) * HDq + p * 32 + sk,
                 Ks[nxt] + u * 512 + lane * 8);
        gl2lds16(Vg + (size_t)(g * 16 + sr) * Sq + (jt + 1) * 64 + p * 32 + sk,
                 Vs[nxt] + u * 512 + lane * 8);
      }
    }

    const bf16_t* Kc = Ks[cur];
    const bf16_t* Vc = Vs[cur];

    // ---- S = Q K^T (exp2 domain) ----
    f32x4 sc[2][4];
#pragma unroll
    for (int mi = 0; mi < 2; ++mi)
#pragma unroll
      for (int nt = 0; nt < 4; ++nt) sc[mi][nt] = (f32x4){0.f, 0.f, 0.f, 0.f};
#pragma unroll
    for (int ks = 0; ks < 2; ++ks)
#pragma unroll
      for (int nt = 0; nt < 4; ++nt) {
        bf16x8 kf = *(const bf16x8*)(Kc + (ks * 4 + nt) * 512 + l15 * 32 + qx * 8);
        sc[0][nt] = __builtin_amdgcn_mfma_f32_16x16x32_bf16(qf[0][ks], kf, sc[0][nt], 0, 0, 0);
        sc[1][nt] = __builtin_amdgcn_mfma_f32_16x16x32_bf16(qf[1][ks], kf, sc[1][nt], 0, 0, 0);
      }

    if (jt >= 2 * qtile) {  // causal mask on diagonal-overlapping tiles
#pragma unroll
      for (int mi = 0; mi < 2; ++mi) {
        int qrow = qtile * 128 + (w * 2 + mi) * 16 + quad * 4;
#pragma unroll
        for (int nt = 0; nt < 4; ++nt) {
          int key = jt * 64 + nt * 16 + l15;
#pragma unroll
          for (int r = 0; r < 4; ++r)
            if (key > qrow + r) sc[mi][nt][r] = -1e30f;
        }
      }
    }

    // ---- p = exp2(s); keys {l15+16nt} -> pos l15*4+nt contiguous: b64 ----
#pragma unroll
    for (int mi = 0; mi < 2; ++mi)
#pragma unroll
      for (int r = 0; r < 4; ++r) {
        bf16x4 pk;
#pragma unroll
        for (int nt = 0; nt < 4; ++nt) {
          float p = fast_exp2(sc[mi][nt][r]);
          lsum[mi][r] += p;
          pk[nt] = (bf16_t)p;
        }
        *(bf16x4*)(Pw + (mi * 16 + quad * 4 + r) * 72 + l15 * 4) = pk;
      }
    // no barrier: Ps[w] wave-private, DS pipe in-order per wave

    // ---- O += P V (k-axis = pos for both operands) ----
#pragma unroll
    for (int kk = 0; kk < 2; ++kk) {
      bf16x8 ap0 = *(const bf16x8*)(Pw + (size_t)l15 * 72 + kk * 32 + quad * 8);
      bf16x8 ap1 = *(const bf16x8*)(Pw + (size_t)(16 + l15) * 72 + kk * 32 + quad * 8);
#pragma unroll
      for (int dt = 0; dt < 4; ++dt) {
        bf16x8 bv = *(const bf16x8*)(Vc + (kk * 4 + dt) * 512 + l15 * 32 + qx * 8);
        o[0][dt] = __builtin_amdgcn_mfma_f32_16x16x32_bf16(ap0, bv, o[0][dt], 0, 0, 0);
        o[1][dt] = __builtin_amdgcn_mfma_f32_16x16x32_bf16(ap1, bv, o[1][dt], 0, 0, 0);
      }
    }
  }

  float linv[2][4];
#pragma unroll
  for (int mi = 0; mi < 2; ++mi)
#pragma unroll
    for (int r = 0; r < 4; ++r) {
      float s = lsum[mi][r];
#pragma unroll
      for (int off = 8; off > 0; off >>= 1) s += __shfl_xor(s, off);
      linv[mi][r] = 1.f / s;
    }

#pragma unroll
  for (int mi = 0; mi < 2; ++mi) {
    int s0 = qtile * 128 + (w * 2 + mi) * 16 + quad * 4;
#pragma unroll
    for (int dt = 0; dt < 4; ++dt) {
      int col = h * 64 + dt * 16 + l15;
#pragma unroll
      for (int r = 0; r < 4; ++r)
        aw[((size_t)b * Sq + s0 + r) * NXq + col] = (bf16_t)(o[mi][dt][r] * linv[mi][r]);
    }
  }
}

// ---------------------------------------------------------------------------
// k4: output projection GEMM -> fp32 out + bias
// ---------------------------------------------------------------------------
__global__ __launch_bounds__(256) void gemm_proj(
    const bf16_t* __restrict__ Aa, const bf16_t* __restrict__ Wt,
    const float* __restrict__ bias, float* __restrict__ out) {
  __shared__ __align__(16) bf16_t As[128 * 32];
  __shared__ __align__(16) bf16_t Bs[128 * 32];
  const int tid = threadIdx.x, lane = tid & 63, w = tid >> 6;
  const int m0 = blockIdx.y * 128, n0 = blockIdx.x * 128;
  f32x4 acc[4][4];
#pragma unroll
  for (int mi = 0; mi < 4; ++mi)
#pragma unroll
    for (int ni = 0; ni < 4; ++ni) acc[mi][ni] = (f32x4){0.f, 0.f, 0.f, 0.f};
  gemm_main(Aa + (size_t)m0 * NXq, Wt + (size_t)n0 * NXq, NXq, acc, As, Bs, lane, w);

  const int wy = w >> 1, wx = w & 1, l15 = lane & 15, quad = lane >> 4;
#pragma unroll
  for (int mi = 0; mi < 4; ++mi) {
    int rowb = m0 + wy * 64 + mi * 16 + quad * 4;
#pragma unroll
    for (int ni = 0; ni < 4; ++ni) {
      int col = n0 + wx * 64 + ni * 16 + l15;
      float bv = bias[col];
#pragma unroll
      for (int r = 0; r < 4; ++r)
        out[(size_t)(rowb + r) * NXq + col] = acc[mi][ni][r] + bv;
    }
  }
}

// ---------------------------------------------------------------------------
// launch
// ---------------------------------------------------------------------------
extern "C" void kernel_launch(void* const* d_in, const int* in_sizes, int n_in,
                              void* d_out, int out_size, void* d_ws, size_t ws_size,
                              hipStream_t stream) {
  const float* hidden   = (const float*)d_in[0];
  const float* c_attn_w = (const float*)d_in[1];
  const float* c_attn_b = (const float*)d_in[2];
  const float* c_proj_w = (const float*)d_in[3];
  const float* c_proj_b = (const float*)d_in[4];
  float* out = (float*)d_out;

  char* ws = (char*)d_ws;
  const size_t szX   = (size_t)8192 * 1024 * 2;
  const size_t szW1  = (size_t)3072 * 1024 * 2;
  const size_t szW2  = (size_t)1024 * 1024 * 2;
  const size_t szQKV = (size_t)Bq * NHq * Sq * HDq * 2;
  bf16_t* Xb  = (bf16_t*)(ws);
  bf16_t* Wt1 = (bf16_t*)(ws + szX);
  bf16_t* Wt2 = (bf16_t*)(ws + szX + szW1);
  bf16_t* qwp = (bf16_t*)(ws + szX + szW1 + szW2);
  bf16_t* kwp = (bf16_t*)(ws + szX + szW1 + szW2 + szQKV);
  bf16_t* vtp = (bf16_t*)(ws + szX + szW1 + szW2 + 2 * szQKV);
  bf16_t* awp = (bf16_t*)(ws + szX + szW1 + szW2 + 3 * szQKV);
  if (ws_size < szX + szW1 + szW2 + 4 * szQKV) return;

  cvt_bf16<<<dim3((8192 * 1024) / (256 * 4)), dim3(256), 0, stream>>>(
      hidden, Xb, 8192 * 1024);
  transpose_cvt<<<dim3(3072 / 32, 1024 / 32), dim3(32, 8), 0, stream>>>(
      c_attn_w, Wt1, 1024, 3072);
  transpose_cvt<<<dim3(1024 / 32, 1024 / 32), dim3(32, 8), 0, stream>>>(
      c_proj_w, Wt2, 1024, 1024);
  gemm_qkv<<<dim3(3072 / 128, 8192 / 128), dim3(256), 0, stream>>>(
      Xb, Wt1, c_attn_b, qwp, kwp, vtp);
  attn_fwd<<<dim3(1024), dim3(256), 0, stream>>>(qwp, kwp, vtp, awp);
  gemm_proj<<<dim3(1024 / 128, 8192 / 128), dim3(256), 0, stream>>>(
      awp, Wt2, c_proj_b, out);
}

// Round 7
// 247.226 us; speedup vs baseline: 1.0807x; 1.0807x over previous
//
#include <hip/hip_runtime.h>

// ============================================================================
// GPT-2 attention block on gfx950, bf16 MFMA throughout.
//
// R7: recovery + two orthogonal low-risk wins.
//  - Revert R6 swizzle entirely (R6 evidence: conflicts 6.3M->0 yet SLOWER —
//    LDS conflicts are free under MFMA+TLP; the swizzled global addresses
//    broke staging lane-merge). Back to R2 staging/fragments/epilogues.
//  - prep kernel: cvt_bf16 + both weight transposes fused into ONE launch.
//  - GEMM grids transposed (x = M-tile, fast dim): consecutive blocks ->
//    different XCDs share the same weight column-slab (~768 KB/XCD L2)
//    instead of thrashing the full W; X streams via LLC.
// ============================================================================

typedef __bf16 bf16_t;
typedef __bf16 bf16x8 __attribute__((ext_vector_type(8)));
typedef __bf16 bf16x4 __attribute__((ext_vector_type(4)));
typedef float  f32x4  __attribute__((ext_vector_type(4)));

#define DI __device__ __forceinline__

static constexpr int Bq = 4, Sq = 2048, NXq = 1024, NHq = 16, HDq = 64;

DI void gl2lds16(const void* g, void* l) {
#if defined(__has_builtin)
#if __has_builtin(__builtin_amdgcn_global_load_lds)
  __builtin_amdgcn_global_load_lds(
      (const __attribute__((address_space(1))) void*)g,
      (__attribute__((address_space(3))) void*)l, 16, 0, 0);
  return;
#endif
#endif
  *(bf16x8*)l = *(const bf16x8*)g;
}

DI float fast_exp2(float x) {
#if defined(__has_builtin)
#if __has_builtin(__builtin_amdgcn_exp2f)
  return __builtin_amdgcn_exp2f(x);
#else
  return exp2f(x);
#endif
#else
  return exp2f(x);
#endif
}

// ---------------------------------------------------------------------------
// k0: fused prep — X fp32->bf16 (blocks 0..2047), W1 transpose+cvt
// (blocks 2048..5119), W2 transpose+cvt (blocks 5120..6143).
// ---------------------------------------------------------------------------
__global__ __launch_bounds__(256) void prep(
    const float* __restrict__ X, const float* __restrict__ W1,
    const float* __restrict__ W2, bf16_t* __restrict__ Xb,
    bf16_t* __restrict__ Wt1, bf16_t* __restrict__ Wt2) {
  __shared__ float t[32][33];
  const int id = blockIdx.x, tid = threadIdx.x;
  if (id < 2048) {
    // cvt: 4096 elems/block, 16/thread as 4x float4
    const float* src = X + (size_t)id * 4096;
    bf16_t* dst = Xb + (size_t)id * 4096;
#pragma unroll
    for (int i = 0; i < 4; ++i) {
      float4 v = *(const float4*)(src + i * 1024 + tid * 4);
      bf16x4 o;
      o[0] = (bf16_t)v.x; o[1] = (bf16_t)v.y; o[2] = (bf16_t)v.z; o[3] = (bf16_t)v.w;
      *(bf16x4*)(dst + i * 1024 + tid * 4) = o;
    }
    return;
  }
  const float* in; bf16_t* out; int R, C, bx, by;
  if (id < 5120) {  // W1 [1024][3072] -> Wt1 [3072][1024]
    int tI = id - 2048; R = 1024; C = 3072; in = W1; out = Wt1;
    bx = (tI % 96) * 32; by = (tI / 96) * 32;
  } else {          // W2 [1024][1024] -> Wt2 [1024][1024]
    int tI = id - 5120; R = 1024; C = 1024; in = W2; out = Wt2;
    bx = (tI % 32) * 32; by = (tI / 32) * 32;
  }
  int tx = tid & 31, ty = tid >> 5;
#pragma unroll
  for (int i = 0; i < 32; i += 8)
    t[ty + i][tx] = in[(size_t)(by + ty + i) * C + bx + tx];
  __syncthreads();
#pragma unroll
  for (int i = 0; i < 32; i += 8)
    out[(size_t)(bx + ty + i) * R + by + tx] = (bf16_t)t[tx][ty + i];
}

// ---------------------------------------------------------------------------
// GEMM main loop (m97 structure, BK=32 — exact R2 config)
// ---------------------------------------------------------------------------
DI void gemm_main(const bf16_t* __restrict__ A, const bf16_t* __restrict__ Bt,
                  int K, f32x4 acc[4][4], bf16_t* As, bf16_t* Bs,
                  int lane, int w) {
  const int wy = w >> 1, wx = w & 1;
  const int l15 = lane & 15, quad = lane >> 4;
  for (int kt = 0; kt < K; kt += 32) {
    __syncthreads();
#pragma unroll
    for (int i = 0; i < 2; ++i) {
      int g = w * 2 + i;
      int row = g * 16 + (lane >> 2);
      int ko = kt + (lane & 3) * 8;
      gl2lds16(A + (size_t)row * K + ko, As + g * 512 + lane * 8);
      gl2lds16(Bt + (size_t)row * K + ko, Bs + g * 512 + lane * 8);
    }
    __syncthreads();
    bf16x8 af[4], bfr[4];
#pragma unroll
    for (int mi = 0; mi < 4; ++mi)
      af[mi] = *(const bf16x8*)(As + (wy * 64 + mi * 16 + l15) * 32 + quad * 8);
#pragma unroll
    for (int ni = 0; ni < 4; ++ni)
      bfr[ni] = *(const bf16x8*)(Bs + (wx * 64 + ni * 16 + l15) * 32 + quad * 8);
#pragma unroll
    for (int mi = 0; mi < 4; ++mi)
#pragma unroll
      for (int ni = 0; ni < 4; ++ni)
        acc[mi][ni] = __builtin_amdgcn_mfma_f32_16x16x32_bf16(
            af[mi], bfr[ni], acc[mi][ni], 0, 0, 0);
  }
}

// ---------------------------------------------------------------------------
// k2: QKV GEMM (R2 epilogue). Grid (64,24): x = M-tile (fast) for XCD/L2
// locality on the weight slab; y = N-tile.
// ---------------------------------------------------------------------------
__global__ __launch_bounds__(256) void gemm_qkv(
    const bf16_t* __restrict__ X, const bf16_t* __restrict__ Wt,
    const float* __restrict__ bias, bf16_t* __restrict__ qw,
    bf16_t* __restrict__ kw, bf16_t* __restrict__ vtw) {
  __shared__ __align__(16) bf16_t As[128 * 32];
  __shared__ __align__(16) bf16_t Bs[128 * 32];
  const int tid = threadIdx.x, lane = tid & 63, w = tid >> 6;
  const int m0 = blockIdx.x * 128, n0 = blockIdx.y * 128;
  f32x4 acc[4][4];
#pragma unroll
  for (int mi = 0; mi < 4; ++mi)
#pragma unroll
    for (int ni = 0; ni < 4; ++ni) acc[mi][ni] = (f32x4){0.f, 0.f, 0.f, 0.f};
  gemm_main(X + (size_t)m0 * NXq, Wt + (size_t)n0 * NXq, NXq, acc, As, Bs, lane, w);

  const int wy = w >> 1, wx = w & 1, l15 = lane & 15, quad = lane >> 4;
  const float qscale = 0.125f * 1.44269504088896340736f;
#pragma unroll
  for (int mi = 0; mi < 4; ++mi) {
    int rowb = m0 + wy * 64 + mi * 16 + quad * 4;
    int bb = rowb >> 11, sl = rowb & 2047;
#pragma unroll
    for (int ni = 0; ni < 4; ++ni) {
      int col = n0 + wx * 64 + ni * 16 + l15;
      float bv = bias[col];
      f32x4 v = acc[mi][ni];
      int sec = col >> 10;
      int c = col & 1023;
      int h = c >> 6, d = c & 63;
      if (sec == 0) {
#pragma unroll
        for (int r = 0; r < 4; ++r)
          qw[(((size_t)bb * NHq + h) * Sq + sl + r) * HDq + d] =
              (bf16_t)((v[r] + bv) * qscale);
      } else if (sec == 1) {
#pragma unroll
        for (int r = 0; r < 4; ++r)
          kw[(((size_t)bb * NHq + h) * Sq + sl + r) * HDq + d] = (bf16_t)(v[r] + bv);
      } else {
        bf16x4 t;
#pragma unroll
        for (int r = 0; r < 4; ++r) t[r] = (bf16_t)(v[r] + bv);
        *(bf16x4*)(vtw + (((size_t)bb * NHq + h) * HDq + d) * Sq + sl) = t;
      }
    }
  }
}

// ---------------------------------------------------------------------------
// k3: flash attention, causal (exact R2 version). BQ=128, BK=64,
// 2 barriers/iter, no-max exp2 softmax, P wave-private LDS, 4 blocks/CU.
// ---------------------------------------------------------------------------
__global__ __launch_bounds__(256, 4) void attn_fwd(
    const bf16_t* __restrict__ qw, const bf16_t* __restrict__ kw,
    const bf16_t* __restrict__ vtw, bf16_t* __restrict__ aw) {
  __shared__ __align__(16) bf16_t Ks[4096], Vs[4096];
  __shared__ __align__(16) bf16_t Ps[4][32 * 72];
  const int tid = threadIdx.x, lane = tid & 63, w = tid >> 6;
  const int l15 = lane & 15, quad = lane >> 4;

  const int id = blockIdx.x;
  const int bh = ((id & 7) << 3) | ((id >> 3) & 7);
  const int k4 = (id >> 6) & 3, quarter = id >> 8;
  int qtile;
  if (quarter == 0)      qtile = 15 - k4;
  else if (quarter == 1) qtile = 8 + k4;
  else if (quarter == 2) qtile = 7 - k4;
  else                   qtile = k4;
  const int b = bh >> 4, h = bh & 15;

  const bf16_t* Qg = qw + ((size_t)bh * Sq + qtile * 128) * HDq;
  const bf16_t* Kg = kw + (size_t)bh * Sq * HDq;
  const bf16_t* Vg = vtw + (size_t)bh * HDq * Sq;

  bf16x8 qf[2][2];
#pragma unroll
  for (int mi = 0; mi < 2; ++mi)
#pragma unroll
    for (int ks = 0; ks < 2; ++ks)
      qf[mi][ks] = *(const bf16x8*)(
          Qg + (size_t)((w * 2 + mi) * 16 + l15) * HDq + ks * 32 + quad * 8);

  f32x4 o[2][4];
  float lsum[2][4];
#pragma unroll
  for (int mi = 0; mi < 2; ++mi) {
#pragma unroll
    for (int dt = 0; dt < 4; ++dt) o[mi][dt] = (f32x4){0.f, 0.f, 0.f, 0.f};
#pragma unroll
    for (int r = 0; r < 4; ++r) lsum[mi][r] = 0.f;
  }

  bf16_t* Pw = &Ps[w][0];
  const int jmax = 2 * qtile + 2;
  for (int jt = 0; jt < jmax; ++jt) {
    __syncthreads();
#pragma unroll
    for (int i = 0; i < 2; ++i) {
      int u = w * 2 + i, p = u >> 2, g = u & 3;
      gl2lds16(Kg + (size_t)(jt * 64 + g * 16 + (lane >> 2)) * HDq + p * 32 + (lane & 3) * 8,
               Ks + u * 512 + lane * 8);
      gl2lds16(Vg + (size_t)(g * 16 + (lane >> 2)) * Sq + jt * 64 + p * 32 + (lane & 3) * 8,
               Vs + u * 512 + lane * 8);
    }
    __syncthreads();

    f32x4 sc[2][4];
#pragma unroll
    for (int mi = 0; mi < 2; ++mi)
#pragma unroll
      for (int nt = 0; nt < 4; ++nt) sc[mi][nt] = (f32x4){0.f, 0.f, 0.f, 0.f};
#pragma unroll
    for (int ks = 0; ks < 2; ++ks)
#pragma unroll
      for (int nt = 0; nt < 4; ++nt) {
        bf16x8 kf = *(const bf16x8*)(Ks + ks * 2048 + nt * 512 + (l15 * 4 + quad) * 8);
        sc[0][nt] = __builtin_amdgcn_mfma_f32_16x16x32_bf16(qf[0][ks], kf, sc[0][nt], 0, 0, 0);
        sc[1][nt] = __builtin_amdgcn_mfma_f32_16x16x32_bf16(qf[1][ks], kf, sc[1][nt], 0, 0, 0);
      }

    if (jt >= 2 * qtile) {
#pragma unroll
      for (int mi = 0; mi < 2; ++mi) {
        int qrow = qtile * 128 + (w * 2 + mi) * 16 + quad * 4;
#pragma unroll
        for (int nt = 0; nt < 4; ++nt) {
          int key = jt * 64 + nt * 16 + l15;
#pragma unroll
          for (int r = 0; r < 4; ++r)
            if (key > qrow + r) sc[mi][nt][r] = -1e30f;
        }
      }
    }

#pragma unroll
    for (int mi = 0; mi < 2; ++mi)
#pragma unroll
      for (int nt = 0; nt < 4; ++nt)
#pragma unroll
        for (int r = 0; r < 4; ++r) {
          float p = fast_exp2(sc[mi][nt][r]);
          lsum[mi][r] += p;
          Pw[(mi * 16 + quad * 4 + r) * 72 + nt * 16 + l15] = (bf16_t)p;
        }
    // no barrier: Ps[w] wave-private, DS pipe in-order per wave

#pragma unroll
    for (int kk = 0; kk < 2; ++kk) {
      bf16x8 ap0 = *(const bf16x8*)(Pw + (size_t)l15 * 72 + kk * 32 + quad * 8);
      bf16x8 ap1 = *(const bf16x8*)(Pw + (size_t)(16 + l15) * 72 + kk * 32 + quad * 8);
#pragma unroll
      for (int dt = 0; dt < 4; ++dt) {
        bf16x8 bv = *(const bf16x8*)(Vs + kk * 2048 + dt * 512 + (l15 * 4 + quad) * 8);
        o[0][dt] = __builtin_amdgcn_mfma_f32_16x16x32_bf16(ap0, bv, o[0][dt], 0, 0, 0);
        o[1][dt] = __builtin_amdgcn_mfma_f32_16x16x32_bf16(ap1, bv, o[1][dt], 0, 0, 0);
      }
    }
  }

  float linv[2][4];
#pragma unroll
  for (int mi = 0; mi < 2; ++mi)
#pragma unroll
    for (int r = 0; r < 4; ++r) {
      float s = lsum[mi][r];
#pragma unroll
      for (int off = 8; off > 0; off >>= 1) s += __shfl_xor(s, off);
      linv[mi][r] = 1.f / s;
    }

#pragma unroll
  for (int mi = 0; mi < 2; ++mi) {
    int s0 = qtile * 128 + (w * 2 + mi) * 16 + quad * 4;
#pragma unroll
    for (int dt = 0; dt < 4; ++dt) {
      int col = h * 64 + dt * 16 + l15;
#pragma unroll
      for (int r = 0; r < 4; ++r)
        aw[((size_t)b * Sq + s0 + r) * NXq + col] = (bf16_t)(o[mi][dt][r] * linv[mi][r]);
    }
  }
}

// ---------------------------------------------------------------------------
// k4: output projection GEMM -> fp32 out + bias. Grid (64,8): x = M-tile.
// ---------------------------------------------------------------------------
__global__ __launch_bounds__(256) void gemm_proj(
    const bf16_t* __restrict__ Aa, const bf16_t* __restrict__ Wt,
    const float* __restrict__ bias, float* __restrict__ out) {
  __shared__ __align__(16) bf16_t As[128 * 32];
  __shared__ __align__(16) bf16_t Bs[128 * 32];
  const int tid = threadIdx.x, lane = tid & 63, w = tid >> 6;
  const int m0 = blockIdx.x * 128, n0 = blockIdx.y * 128;
  f32x4 acc[4][4];
#pragma unroll
  for (int mi = 0; mi < 4; ++mi)
#pragma unroll
    for (int ni = 0; ni < 4; ++ni) acc[mi][ni] = (f32x4){0.f, 0.f, 0.f, 0.f};
  gemm_main(Aa + (size_t)m0 * NXq, Wt + (size_t)n0 * NXq, NXq, acc, As, Bs, lane, w);

  const int wy = w >> 1, wx = w & 1, l15 = lane & 15, quad = lane >> 4;
#pragma unroll
  for (int mi = 0; mi < 4; ++mi) {
    int rowb = m0 + wy * 64 + mi * 16 + quad * 4;
#pragma unroll
    for (int ni = 0; ni < 4; ++ni) {
      int col = n0 + wx * 64 + ni * 16 + l15;
      float bv = bias[col];
#pragma unroll
      for (int r = 0; r < 4; ++r)
        out[(size_t)(rowb + r) * NXq + col] = acc[mi][ni][r] + bv;
    }
  }
}

// ---------------------------------------------------------------------------
// launch
// ---------------------------------------------------------------------------
extern "C" void kernel_launch(void* const* d_in, const int* in_sizes, int n_in,
                              void* d_out, int out_size, void* d_ws, size_t ws_size,
                              hipStream_t stream) {
  const float* hidden   = (const float*)d_in[0];
  const float* c_attn_w = (const float*)d_in[1];
  const float* c_attn_b = (const float*)d_in[2];
  const float* c_proj_w = (const float*)d_in[3];
  const float* c_proj_b = (const float*)d_in[4];
  float* out = (float*)d_out;

  char* ws = (char*)d_ws;
  const size_t szX   = (size_t)8192 * 1024 * 2;
  const size_t szW1  = (size_t)3072 * 1024 * 2;
  const size_t szW2  = (size_t)1024 * 1024 * 2;
  const size_t szQKV = (size_t)Bq * NHq * Sq * HDq * 2;
  bf16_t* Xb  = (bf16_t*)(ws);
  bf16_t* Wt1 = (bf16_t*)(ws + szX);
  bf16_t* Wt2 = (bf16_t*)(ws + szX + szW1);
  bf16_t* qwp = (bf16_t*)(ws + szX + szW1 + szW2);
  bf16_t* kwp = (bf16_t*)(ws + szX + szW1 + szW2 + szQKV);
  bf16_t* vtp = (bf16_t*)(ws + szX + szW1 + szW2 + 2 * szQKV);
  bf16_t* awp = (bf16_t*)(ws + szX + szW1 + szW2 + 3 * szQKV);
  if (ws_size < szX + szW1 + szW2 + 4 * szQKV) return;

  prep<<<dim3(6144), dim3(256), 0, stream>>>(hidden, c_attn_w, c_proj_w,
                                             Xb, Wt1, Wt2);
  gemm_qkv<<<dim3(64, 24), dim3(256), 0, stream>>>(
      Xb, Wt1, c_attn_b, qwp, kwp, vtp);
  attn_fwd<<<dim3(1024), dim3(256), 0, stream>>>(qwp, kwp, vtp, awp);
  gemm_proj<<<dim3(64, 8), dim3(256), 0, stream>>>(
      awp, Wt2, c_proj_b, out);
}